// Round 6
// baseline (90.521 us; speedup 1.0000x reference)
//
#include <hip/hip_runtime.h>
#include <math.h>

#define Bb   64
#define Nn   8192
#define Dd   64
#define Cc   256
#define INn  128
#define CTRL 192
#define OUTW 320
#define EPSF 1e-8f
#define BN   (Bb*Nn)

// ---------------- workspace layout (floats) ----------------
#define OFF_P4  0                     // packed per-row {xw, dr, c5, nq}   [BN*4]
#define OFF_P2  (4*BN)                // packed per-row {e1, e2}; e1 slot becomes x_r after k_rside
#define OFF_WPW (6*BN)                // unnormalized wpow_w               [BN]
#define OFF_WPR (7*BN)                // unnormalized wpow_r               [BN]
#define OFF_PT  (8*BN)                // read-vec partials                 [2048*64]
#define OFF_MS  (OFF_PT + 2048*64)    // W-side online {M, S} per block    [2048*2]
#define OFF_PW  (OFF_MS + 4096)       // W-side powsum partials            [2048]
#define OFF_MSR (OFF_PW + 2048)       // R-side online {M, S} per block    [2048*2]
#define OFF_PR  (OFF_MSR + 4096)      // R-side powsum partials            [2048]
#define OFF_KW  (OFF_PR + 2048)       // k_w                               [B*D]
#define OFF_KR  (OFF_KW + Bb*Dd)      // k_r                               [B*D]
#define OFF_ER  (OFF_KR + Bb*Dd)      // erase (post-sigmoid)              [B*D]
#define OFF_AD  (OFF_ER + Bb*Dd)      // add (post-tanh)                   [B*D]
#define OFF_SC  (OFF_AD + Bb*Dd)      // per-b scalars                     [B*16]
// per-b scalars: 0..3 beta_w,g_w,gam_w,knorm_w | 4..7 beta_r,g_r,gam_r,knorm_r
//                8..10 s_w | 11 AK=a.k_r | 12..14 s_r | 15 A2=|a|^2

__device__ __forceinline__ float softplusf(float x) {
    return (x > 20.f) ? x : log1pf(__expf(x));
}
__device__ __forceinline__ float sigmoidf(float x) {
    return 1.f / (1.f + __expf(-x));
}
// online-softmax pair combine: (m,s) <- (m,s) (+) (m2,s2)
__device__ __forceinline__ void msCombine(float& m, float& s, float m2, float s2) {
    const float mn = fmaxf(m, m2);
    s = s * __expf(m - mn) + s2 * __expf(m2 - mn);
    m = mn;
}

struct SetupArgs {
    const float *x, *prv, *Wc, *bc;
    const float *Wk_r, *bk_r, *Wb_r, *bb_r, *Wg_r, *bg_r, *Ws_r, *bs_r, *Wgam_r, *bgam_r;
    const float *Wk_w, *bk_w, *Wb_w, *bb_w, *Wg_w, *bg_w, *Ws_w, *bs_w, *Wgam_w, *bgam_w;
    const float *We_w, *be_w, *Wa_w, *ba_w;
    float *ws, *out;
};

// one block per batch: controller GEMM + projections + batched scalar reductions
__global__ __launch_bounds__(256) void k_setup(SetupArgs a) {
    __shared__ float ci[CTRL];
    __shared__ float h[Cc];
    __shared__ alignas(16) float kbuf[128];
    __shared__ alignas(16) float abuf[64];
    __shared__ float red[4][16];
    __shared__ float sums[16];
    const int b = blockIdx.x, t = threadIdx.x;

    if (t < INn)       ci[t] = a.x[b * INn + t];
    else if (t < CTRL) ci[t] = a.prv[b * Dd + (t - INn)];
    __syncthreads();

    float acc = a.bc[t];
    #pragma unroll 16
    for (int i = 0; i < CTRL; ++i) acc += ci[i] * a.Wc[i * Cc + t];
    const float hv = fmaxf(acc, 0.f);
    h[t] = hv;
    a.out[b * OUTW + t] = hv;
    __syncthreads();

    {
        const int job = t >> 6, d = t & 63;
        const float* W  = (job == 0) ? a.Wk_w : (job == 1) ? a.Wk_r : (job == 2) ? a.We_w : a.Wa_w;
        const float* bs = (job == 0) ? a.bk_w : (job == 1) ? a.bk_r : (job == 2) ? a.be_w : a.ba_w;
        float p = bs[d];
        #pragma unroll 16
        for (int c = 0; c < Cc; ++c) p += h[c] * W[c * Dd + d];
        if (job == 0)      { a.ws[OFF_KW + b * Dd + d] = p; kbuf[d] = p; }
        else if (job == 1) { a.ws[OFF_KR + b * Dd + d] = p; kbuf[64 + d] = p; }
        else if (job == 2) { a.ws[OFF_ER + b * Dd + d] = sigmoidf(p); }
        else               { const float ad = tanhf(p); a.ws[OFF_AD + b * Dd + d] = ad; abuf[d] = ad; }
    }
    __syncthreads();

    float v[16];
    v[0] = hv * a.Wb_w[t];  v[1] = hv * a.Wg_w[t];  v[2] = hv * a.Wgam_w[t];
    v[3] = hv * a.Ws_w[t * 3 + 0]; v[4] = hv * a.Ws_w[t * 3 + 1]; v[5] = hv * a.Ws_w[t * 3 + 2];
    v[6] = hv * a.Wb_r[t];  v[7] = hv * a.Wg_r[t];  v[8] = hv * a.Wgam_r[t];
    v[9] = hv * a.Ws_r[t * 3 + 0]; v[10] = hv * a.Ws_r[t * 3 + 1]; v[11] = hv * a.Ws_r[t * 3 + 2];
    v[12] = (t < 64) ? kbuf[t] * kbuf[t] : 0.f;
    v[13] = (t >= 64 && t < 128) ? kbuf[t] * kbuf[t] : 0.f;
    v[14] = (t < 64) ? abuf[t] * kbuf[64 + t] : 0.f;
    v[15] = (t < 64) ? abuf[t] * abuf[t] : 0.f;
    #pragma unroll
    for (int k = 0; k < 16; ++k) {
        #pragma unroll
        for (int m = 32; m >= 1; m >>= 1) v[k] += __shfl_xor(v[k], m);
    }
    if ((t & 63) == 0) {
        #pragma unroll
        for (int k = 0; k < 16; ++k) red[t >> 6][k] = v[k];
    }
    __syncthreads();
    if (t < 16) sums[t] = red[0][t] + red[1][t] + red[2][t] + red[3][t];
    __syncthreads();

    if (t == 0) {
        float* sc = a.ws + OFF_SC + b * 16;
        sc[0] = softplusf(sums[0] + a.bb_w[0]);
        sc[1] = sigmoidf(sums[1] + a.bg_w[0]);
        sc[2] = softplusf(sums[2] + a.bgam_w[0]) + 1.f;
        sc[3] = sqrtf(sums[12]);
        sc[4] = softplusf(sums[6] + a.bb_r[0]);
        sc[5] = sigmoidf(sums[7] + a.bg_r[0]);
        sc[6] = softplusf(sums[8] + a.bgam_r[0]) + 1.f;
        sc[7] = sqrtf(sums[13]);
        {
            const float v0 = sums[3] + a.bs_w[0], v1 = sums[4] + a.bs_w[1], v2 = sums[5] + a.bs_w[2];
            const float m = fmaxf(fmaxf(v0, v1), v2);
            const float e0 = __expf(v0 - m), e1 = __expf(v1 - m), e2 = __expf(v2 - m);
            const float s = e0 + e1 + e2;
            sc[8] = e0 / s; sc[9] = e1 / s; sc[10] = e2 / s;
        }
        sc[11] = sums[14];
        {
            const float v0 = sums[9] + a.bs_r[0], v1 = sums[10] + a.bs_r[1], v2 = sums[11] + a.bs_r[2];
            const float m = fmaxf(fmaxf(v0, v1), v2);
            const float e0 = __expf(v0 - m), e1 = __expf(v1 - m), e2 = __expf(v2 - m);
            const float s = e0 + e1 + e2;
            sc[12] = e0 / s; sc[13] = e1 / s; sc[14] = e2 / s;
        }
        sc[15] = sums[15];
    }
}

// streaming pass: 2048 blocks x 256 thr. 8 lanes per row, 8 cols/lane.
// Produces packed per-row scalars + per-block online softmax {M,S} of x_w.
__global__ __launch_bounds__(256) void k_pass1(const float* __restrict__ mem,
                                               float* __restrict__ ws) {
    __shared__ float redm[4], reds[4];
    const int t = threadIdx.x;
    const int wv = t >> 6, lane = t & 63;
    const int cg = lane & 7;          // col group 0..7
    const int rr = lane >> 3;         // row within 8
    const int wbase = blockIdx.x * 256 + wv * 64;   // 64 rows per wave
    const int b = wbase >> 13;
    const int cb = cg << 3;           // col base

    const float4 kwA = *(const float4*)(ws + OFF_KW + (b << 6) + cb);
    const float4 kwB = *(const float4*)(ws + OFF_KW + (b << 6) + cb + 4);
    const float4 krA = *(const float4*)(ws + OFF_KR + (b << 6) + cb);
    const float4 krB = *(const float4*)(ws + OFF_KR + (b << 6) + cb + 4);
    const float4 evA = *(const float4*)(ws + OFF_ER + (b << 6) + cb);
    const float4 evB = *(const float4*)(ws + OFF_ER + (b << 6) + cb + 4);
    const float4 avA = *(const float4*)(ws + OFF_AD + (b << 6) + cb);
    const float4 avB = *(const float4*)(ws + OFF_AD + (b << 6) + cb + 4);
    const float beta = ws[OFF_SC + b * 16 + 0];
    const float kn   = ws[OFF_SC + b * 16 + 3];

    float om = -1e30f, os = 0.f;      // per-lane online (m,s)
    #pragma unroll 2
    for (int it = 0; it < 8; ++it) {
        const int row = wbase + (it << 3) + rr;
        const float* mp = mem + ((size_t)row << 6) + cb;
        const float4 m0 = *(const float4*)(mp);
        const float4 m1 = *(const float4*)(mp + 4);
        float dw = 0.f, dr = 0.f, nq = 0.f, e1 = 0.f, e2 = 0.f, c5 = 0.f;
        #define ACC(mv, kwv, krv, evv, avv) { \
            const float me = (mv) * (evv); \
            dw = fmaf((mv), (kwv), dw); \
            dr = fmaf((mv), (krv), dr); \
            nq = fmaf((mv), (mv), nq); \
            e1 = fmaf((mv), (avv) - me, e1); \
            e2 = fmaf(me, fmaf(-2.f, (avv), me), e2); \
            c5 = fmaf(me, (krv), c5); }
        ACC(m0.x, kwA.x, krA.x, evA.x, avA.x)
        ACC(m0.y, kwA.y, krA.y, evA.y, avA.y)
        ACC(m0.z, kwA.z, krA.z, evA.z, avA.z)
        ACC(m0.w, kwA.w, krA.w, evA.w, avA.w)
        ACC(m1.x, kwB.x, krB.x, evB.x, avB.x)
        ACC(m1.y, kwB.y, krB.y, evB.y, avB.y)
        ACC(m1.z, kwB.z, krB.z, evB.z, avB.z)
        ACC(m1.w, kwB.w, krB.w, evB.w, avB.w)
        #undef ACC
        #pragma unroll
        for (int mk = 1; mk <= 4; mk <<= 1) {
            dw += __shfl_xor(dw, mk); dr += __shfl_xor(dr, mk);
            nq += __shfl_xor(nq, mk); e1 += __shfl_xor(e1, mk);
            e2 += __shfl_xor(e2, mk); c5 += __shfl_xor(c5, mk);
        }
        const float xw = beta * dw / (sqrtf(nq) * kn + EPSF);
        // online update (x duplicated 8x across cg -> corrected at the end)
        if (xw > om) { os = os * __expf(om - xw) + 1.f; om = xw; }
        else         { os += __expf(xw - om); }
        if (cg == 0) {
            float4 p4; p4.x = xw; p4.y = dr; p4.z = c5; p4.w = nq;
            *(float4*)(ws + OFF_P4 + ((size_t)row << 2)) = p4;
            float2 p2; p2.x = e1; p2.y = e2;
            *(float2*)(ws + OFF_P2 + ((size_t)row << 1)) = p2;
        }
    }
    #pragma unroll
    for (int mk = 1; mk <= 32; mk <<= 1) {
        const float m2 = __shfl_xor(om, mk), s2 = __shfl_xor(os, mk);
        msCombine(om, os, m2, s2);
    }
    if (lane == 0) { redm[wv] = om; reds[wv] = os; }
    __syncthreads();
    if (t == 0) {
        float M = redm[0], S = reds[0];
        msCombine(M, S, redm[1], reds[1]);
        msCombine(M, S, redm[2], reds[2]);
        msCombine(M, S, redm[3], reds[3]);
        ws[OFF_MS + (blockIdx.x << 1)]     = M;
        ws[OFF_MS + (blockIdx.x << 1) + 1] = S * 0.125f;   // undo 8x duplication
    }
}

// W-side finalize: 2048 blocks x 256 thr; each block owns 256 rows of one batch.
// wg with 258-row halo in LDS -> shift -> wpow_w (stored) + per-block powsum partial.
__global__ __launch_bounds__(256) void k_wside(const float* __restrict__ prevw_w,
                                               float* __restrict__ ws) {
    __shared__ float wgbuf[258];
    __shared__ float red[6];   // [0..3] powsum, [4] M, [5] invS
    const int blk = blockIdx.x, t = threadIdx.x;
    const int b = blk >> 5;
    const int rbl = (blk & 31) << 8;
    const int bN = b * Nn;

    if (t < 64) {   // wave 0 combines the 32 online pairs
        float m = -1e30f, s = 0.f;
        if (t < 32) {
            m = ws[OFF_MS + (((b << 5) + t) << 1)];
            s = ws[OFF_MS + (((b << 5) + t) << 1) + 1];
        }
        #pragma unroll
        for (int mk = 1; mk <= 32; mk <<= 1) {
            const float m2 = __shfl_xor(m, mk), s2 = __shfl_xor(s, mk);
            msCombine(m, s, m2, s2);
        }
        if (t == 0) { red[4] = m; red[5] = 1.f / s; }
    }
    __syncthreads();
    const float M = red[4], invS = red[5];
    const float* sc = ws + OFF_SC + b * 16;
    const float g = sc[1], gam = sc[2];
    const float s0 = sc[8], s1 = sc[9], s2 = sc[10];

    auto wg_at = [&](int i) {   // i in [0,258) maps to local row (rbl+i-1) mod N
        const int rg = bN + ((rbl + i - 1) & (Nn - 1));
        const float xw = ws[OFF_P4 + ((size_t)rg << 2)];
        return g * __expf(xw - M) * invS + (1.f - g) * prevw_w[rg];
    };
    wgbuf[t + 1] = wg_at(t + 1);
    if (t == 0)   wgbuf[0]   = wg_at(0);
    if (t == 255) wgbuf[257] = wg_at(257);
    __syncthreads();

    const float wsv = s0 * wgbuf[t + 2] + s1 * wgbuf[t + 1] + s2 * wgbuf[t];
    const float wp = __expf(gam * __logf(wsv));
    ws[OFF_WPW + bN + rbl + t] = wp;

    float v = wp;
    #pragma unroll
    for (int mk = 1; mk <= 32; mk <<= 1) v += __shfl_xor(v, mk);
    if ((t & 63) == 0) red[t >> 6] = v;
    __syncthreads();
    if (t == 0) ws[OFF_PW + blk] = red[0] + red[1] + red[2] + red[3];
}

// R-side sim: normalize ww, expanded cosine sim vs new_mem, online {M,S} partials.
__global__ __launch_bounds__(256) void k_rside(float* __restrict__ ws) {
    __shared__ float redm[4], reds[4];
    __shared__ float inv[1];
    const int blk = blockIdx.x, t = threadIdx.x;
    const int b = blk >> 5;
    const int rbl = (blk & 31) << 8;
    const int bN = b * Nn;

    if (t < 64) {
        float v = (t < 32) ? ws[OFF_PW + (b << 5) + t] : 0.f;
        #pragma unroll
        for (int mk = 1; mk <= 32; mk <<= 1) v += __shfl_xor(v, mk);
        if (t == 0) inv[0] = 1.f / (v + EPSF);
    }
    __syncthreads();
    const float invW = inv[0];
    const float* sc = ws + OFF_SC + b * 16;
    const float beta_r = sc[4], kn_r = sc[7], AK = sc[11], A2 = sc[15];

    const int row = bN + rbl + t;
    const float ww = ws[OFF_WPW + row] * invW;
    const float4 p4 = *(const float4*)(ws + OFF_P4 + ((size_t)row << 2));
    const float2 p2 = *(const float2*)(ws + OFF_P2 + ((size_t)row << 1));
    const float d = p4.y + ww * (AK - p4.z);
    float qq = p4.w + 2.f * ww * p2.x + ww * ww * (p2.y + A2);
    qq = fmaxf(qq, 0.f);
    const float x = beta_r * d / (sqrtf(qq) * kn_r + EPSF);
    ws[OFF_P2 + ((size_t)row << 1)] = x;    // x_r into the e1 slot

    float om = x, os = 1.f;
    #pragma unroll
    for (int mk = 1; mk <= 32; mk <<= 1) {
        const float m2 = __shfl_xor(om, mk), s2 = __shfl_xor(os, mk);
        msCombine(om, os, m2, s2);
    }
    if ((t & 63) == 0) { redm[t >> 6] = om; reds[t >> 6] = os; }
    __syncthreads();
    if (t == 0) {
        float M = redm[0], S = reds[0];
        msCombine(M, S, redm[1], reds[1]);
        msCombine(M, S, redm[2], reds[2]);
        msCombine(M, S, redm[3], reds[3]);
        ws[OFF_MSR + (blk << 1)]     = M;
        ws[OFF_MSR + (blk << 1) + 1] = S;
    }
}

// R-side finalize: wg_r halo -> shift -> wpow_r (stored) + powsum partial.
__global__ __launch_bounds__(256) void k_rfin(const float* __restrict__ prevw_r,
                                              float* __restrict__ ws) {
    __shared__ float wgbuf[258];
    __shared__ float red[6];
    const int blk = blockIdx.x, t = threadIdx.x;
    const int b = blk >> 5;
    const int rbl = (blk & 31) << 8;
    const int bN = b * Nn;

    if (t < 64) {
        float m = -1e30f, s = 0.f;
        if (t < 32) {
            m = ws[OFF_MSR + (((b << 5) + t) << 1)];
            s = ws[OFF_MSR + (((b << 5) + t) << 1) + 1];
        }
        #pragma unroll
        for (int mk = 1; mk <= 32; mk <<= 1) {
            const float m2 = __shfl_xor(m, mk), s2 = __shfl_xor(s, mk);
            msCombine(m, s, m2, s2);
        }
        if (t == 0) { red[4] = m; red[5] = 1.f / s; }
    }
    __syncthreads();
    const float M = red[4], invS = red[5];
    const float* sc = ws + OFF_SC + b * 16;
    const float g = sc[5], gam = sc[6];
    const float s0 = sc[12], s1 = sc[13], s2 = sc[14];

    auto wg_at = [&](int i) {
        const int rg = bN + ((rbl + i - 1) & (Nn - 1));
        const float xr = ws[OFF_P2 + ((size_t)rg << 1)];
        return g * __expf(xr - M) * invS + (1.f - g) * prevw_r[rg];
    };
    wgbuf[t + 1] = wg_at(t + 1);
    if (t == 0)   wgbuf[0]   = wg_at(0);
    if (t == 255) wgbuf[257] = wg_at(257);
    __syncthreads();

    const float wsv = s0 * wgbuf[t + 2] + s1 * wgbuf[t + 1] + s2 * wgbuf[t];
    const float wp = __expf(gam * __logf(wsv));
    ws[OFF_WPR + bN + rbl + t] = wp;

    float v = wp;
    #pragma unroll
    for (int mk = 1; mk <= 32; mk <<= 1) v += __shfl_xor(v, mk);
    if ((t & 63) == 0) red[t >> 6] = v;
    __syncthreads();
    if (t == 0) ws[OFF_PR + blk] = red[0] + red[1] + red[2] + red[3];
}

// read-vector partials: recompute new_mem on the fly (second & last mem pass)
__global__ __launch_bounds__(256) void k_read(const float* __restrict__ mem,
                                              float* __restrict__ ws) {
    __shared__ float lds[4 * 64];
    __shared__ float invb[2];
    const int b = blockIdx.x >> 5;
    const int chunk = blockIdx.x & 31;
    const int t = threadIdx.x;
    const int lane = t & 63, wv = t >> 6;
    const int q = lane & 15, r = lane >> 4;

    if (t < 64) {
        float vw = (t < 32) ? ws[OFF_PW + (b << 5) + t] : 0.f;
        float vr = (t < 32) ? ws[OFF_PR + (b << 5) + t] : 0.f;
        #pragma unroll
        for (int mk = 1; mk <= 32; mk <<= 1) { vw += __shfl_xor(vw, mk); vr += __shfl_xor(vr, mk); }
        if (t == 0) { invb[0] = 1.f / (vw + EPSF); invb[1] = 1.f / (vr + EPSF); }
    }
    __syncthreads();
    const float invW = invb[0], invR = invb[1];

    const float4 evv = *(const float4*)(ws + OFF_ER + (b << 6) + (q << 2));
    const float4 avv = *(const float4*)(ws + OFF_AD + (b << 6) + (q << 2));
    float a0 = 0.f, a1 = 0.f, a2 = 0.f, a3 = 0.f;
    const int base_n = chunk << 8;
    #pragma unroll 4
    for (int gi = wv; gi < 64; gi += 4) {
        const int n = base_n + (gi << 2) + r;
        const int row = b * Nn + n;
        const float4 mv = *(const float4*)(mem + ((size_t)row << 6) + (q << 2));
        const float w   = ws[OFF_WPW + row] * invW;
        const float wrv = ws[OFF_WPR + row] * invR;
        a0 = fmaf((mv.x * (1.f - w * evv.x) + w * avv.x), wrv, a0);
        a1 = fmaf((mv.y * (1.f - w * evv.y) + w * avv.y), wrv, a1);
        a2 = fmaf((mv.z * (1.f - w * evv.z) + w * avv.z), wrv, a2);
        a3 = fmaf((mv.w * (1.f - w * evv.w) + w * avv.w), wrv, a3);
    }
    #pragma unroll
    for (int m = 16; m <= 32; m <<= 1) {
        a0 += __shfl_xor(a0, m); a1 += __shfl_xor(a1, m);
        a2 += __shfl_xor(a2, m); a3 += __shfl_xor(a3, m);
    }
    if (r == 0) {
        lds[wv * 64 + q * 4 + 0] = a0; lds[wv * 64 + q * 4 + 1] = a1;
        lds[wv * 64 + q * 4 + 2] = a2; lds[wv * 64 + q * 4 + 3] = a3;
    }
    __syncthreads();
    if (t < 64) {
        ws[OFF_PT + blockIdx.x * 64 + t] = lds[t] + lds[64 + t] + lds[128 + t] + lds[192 + t];
    }
}

__global__ __launch_bounds__(64) void k_reduce(const float* __restrict__ ws,
                                               float* __restrict__ out) {
    const int b = blockIdx.x, d = threadIdx.x;
    float s = 0.f;
    #pragma unroll
    for (int i = 0; i < 32; ++i) s += ws[OFF_PT + ((b << 5) + i) * 64 + d];
    out[b * OUTW + 256 + d] = s;
}

extern "C" void kernel_launch(void* const* d_in, const int* in_sizes, int n_in,
                              void* d_out, int out_size, void* d_ws, size_t ws_size,
                              hipStream_t stream) {
    const float* x      = (const float*)d_in[0];
    const float* mem    = (const float*)d_in[1];
    const float* prw_r  = (const float*)d_in[2];
    const float* prw_w  = (const float*)d_in[3];
    const float* prv    = (const float*)d_in[4];

    float* ws  = (float*)d_ws;
    float* out = (float*)d_out;

    SetupArgs a;
    a.x = x; a.prv = prv;
    a.Wc = (const float*)d_in[5];  a.bc = (const float*)d_in[6];
    a.Wk_r = (const float*)d_in[7];  a.bk_r = (const float*)d_in[8];
    a.Wb_r = (const float*)d_in[9];  a.bb_r = (const float*)d_in[10];
    a.Wg_r = (const float*)d_in[11]; a.bg_r = (const float*)d_in[12];
    a.Ws_r = (const float*)d_in[13]; a.bs_r = (const float*)d_in[14];
    a.Wgam_r = (const float*)d_in[15]; a.bgam_r = (const float*)d_in[16];
    a.Wk_w = (const float*)d_in[17]; a.bk_w = (const float*)d_in[18];
    a.Wb_w = (const float*)d_in[19]; a.bb_w = (const float*)d_in[20];
    a.Wg_w = (const float*)d_in[21]; a.bg_w = (const float*)d_in[22];
    a.Ws_w = (const float*)d_in[23]; a.bs_w = (const float*)d_in[24];
    a.Wgam_w = (const float*)d_in[25]; a.bgam_w = (const float*)d_in[26];
    a.We_w = (const float*)d_in[27]; a.be_w = (const float*)d_in[28];
    a.Wa_w = (const float*)d_in[29]; a.ba_w = (const float*)d_in[30];
    a.ws = ws; a.out = out;

    k_setup <<<Bb,   256, 0, stream>>>(a);
    k_pass1 <<<2048, 256, 0, stream>>>(mem, ws);
    k_wside <<<2048, 256, 0, stream>>>(prw_w, ws);
    k_rside <<<2048, 256, 0, stream>>>(ws);
    k_rfin  <<<2048, 256, 0, stream>>>(prw_r, ws);
    k_read  <<<2048, 256, 0, stream>>>(mem, ws);
    k_reduce<<<Bb,   64,  0, stream>>>(ws, out);
}

// Round 7
// 83.130 us; speedup vs baseline: 1.0889x; 1.0889x over previous
//
#include <hip/hip_runtime.h>
#include <math.h>

#define Bb   64
#define Nn   8192
#define Dd   64
#define Cc   256
#define INn  128
#define CTRL 192
#define OUTW 320
#define EPSF 1e-8f
#define BN   (Bb*Nn)

// ---------------- workspace layout (floats) ----------------
#define OFF_P4  0                     // packed per-row {xw, dr, c5, nq}   [BN*4]
#define OFF_P2  (4*BN)                // packed per-row {e1, e2}; e1 slot becomes x_r after k_rside
#define OFF_WPW (6*BN)                // unnormalized wpow_w               [BN]
#define OFF_WPR (7*BN)                // unnormalized wpow_r               [BN]
#define OFF_PT  (8*BN)                // read-vec partials                 [2048*64]
#define OFF_MS  (OFF_PT + 2048*64)    // W-side online {M, S} per block    [2048*2]
#define OFF_PW  (OFF_MS + 4096)       // W-side powsum partials            [2048]
#define OFF_MSR (OFF_PW + 2048)       // R-side online {M, S} per block    [2048*2]
#define OFF_PR  (OFF_MSR + 4096)      // R-side powsum partials            [2048]
#define OFF_KW  (OFF_PR + 2048)       // k_w                               [B*D]
#define OFF_KR  (OFF_KW + Bb*Dd)      // k_r                               [B*D]
#define OFF_ER  (OFF_KR + Bb*Dd)      // erase (post-sigmoid)              [B*D]
#define OFF_AD  (OFF_ER + Bb*Dd)      // add (post-tanh)                   [B*D]
#define OFF_SC  (OFF_AD + Bb*Dd)      // per-b scalars                     [B*16]
// per-b scalars: 0..3 beta_w,g_w,gam_w,knorm_w | 4..7 beta_r,g_r,gam_r,knorm_r
//                8..10 s_w | 11 AK=a.k_r | 12..14 s_r | 15 A2=|a|^2

__device__ __forceinline__ float softplusf(float x) {
    return (x > 20.f) ? x : log1pf(__expf(x));
}
__device__ __forceinline__ float sigmoidf(float x) {
    return 1.f / (1.f + __expf(-x));
}
// online-softmax pair combine: (m,s) <- (m,s) (+) (m2,s2)
__device__ __forceinline__ void msCombine(float& m, float& s, float m2, float s2) {
    const float mn = fmaxf(m, m2);
    s = s * __expf(m - mn) + s2 * __expf(m2 - mn);
    m = mn;
}

struct SetupArgs {
    const float *x, *prv, *Wc, *bc;
    const float *Wk_r, *bk_r, *Wb_r, *bb_r, *Wg_r, *bg_r, *Ws_r, *bs_r, *Wgam_r, *bgam_r;
    const float *Wk_w, *bk_w, *Wb_w, *bb_w, *Wg_w, *bg_w, *Ws_w, *bs_w, *Wgam_w, *bgam_w;
    const float *We_w, *be_w, *Wa_w, *ba_w;
    float *ws, *out;
};

// one block per batch: controller GEMM + projections + batched scalar reductions
__global__ __launch_bounds__(256) void k_setup(SetupArgs a) {
    __shared__ float ci[CTRL];
    __shared__ float h[Cc];
    __shared__ alignas(16) float kbuf[128];
    __shared__ alignas(16) float abuf[64];
    __shared__ float red[4][16];
    __shared__ float sums[16];
    const int b = blockIdx.x, t = threadIdx.x;

    if (t < INn)       ci[t] = a.x[b * INn + t];
    else if (t < CTRL) ci[t] = a.prv[b * Dd + (t - INn)];
    __syncthreads();

    float acc = a.bc[t];
    #pragma unroll 16
    for (int i = 0; i < CTRL; ++i) acc += ci[i] * a.Wc[i * Cc + t];
    const float hv = fmaxf(acc, 0.f);
    h[t] = hv;
    a.out[b * OUTW + t] = hv;
    __syncthreads();

    {
        const int job = t >> 6, d = t & 63;
        const float* W  = (job == 0) ? a.Wk_w : (job == 1) ? a.Wk_r : (job == 2) ? a.We_w : a.Wa_w;
        const float* bs = (job == 0) ? a.bk_w : (job == 1) ? a.bk_r : (job == 2) ? a.be_w : a.ba_w;
        float p = bs[d];
        #pragma unroll 16
        for (int c = 0; c < Cc; ++c) p += h[c] * W[c * Dd + d];
        if (job == 0)      { a.ws[OFF_KW + b * Dd + d] = p; kbuf[d] = p; }
        else if (job == 1) { a.ws[OFF_KR + b * Dd + d] = p; kbuf[64 + d] = p; }
        else if (job == 2) { a.ws[OFF_ER + b * Dd + d] = sigmoidf(p); }
        else               { const float ad = tanhf(p); a.ws[OFF_AD + b * Dd + d] = ad; abuf[d] = ad; }
    }
    __syncthreads();

    float v[16];
    v[0] = hv * a.Wb_w[t];  v[1] = hv * a.Wg_w[t];  v[2] = hv * a.Wgam_w[t];
    v[3] = hv * a.Ws_w[t * 3 + 0]; v[4] = hv * a.Ws_w[t * 3 + 1]; v[5] = hv * a.Ws_w[t * 3 + 2];
    v[6] = hv * a.Wb_r[t];  v[7] = hv * a.Wg_r[t];  v[8] = hv * a.Wgam_r[t];
    v[9] = hv * a.Ws_r[t * 3 + 0]; v[10] = hv * a.Ws_r[t * 3 + 1]; v[11] = hv * a.Ws_r[t * 3 + 2];
    v[12] = (t < 64) ? kbuf[t] * kbuf[t] : 0.f;
    v[13] = (t >= 64 && t < 128) ? kbuf[t] * kbuf[t] : 0.f;
    v[14] = (t < 64) ? abuf[t] * kbuf[64 + t] : 0.f;
    v[15] = (t < 64) ? abuf[t] * abuf[t] : 0.f;
    #pragma unroll
    for (int k = 0; k < 16; ++k) {
        #pragma unroll
        for (int m = 32; m >= 1; m >>= 1) v[k] += __shfl_xor(v[k], m);
    }
    if ((t & 63) == 0) {
        #pragma unroll
        for (int k = 0; k < 16; ++k) red[t >> 6][k] = v[k];
    }
    __syncthreads();
    if (t < 16) sums[t] = red[0][t] + red[1][t] + red[2][t] + red[3][t];
    __syncthreads();

    if (t == 0) {
        float* sc = a.ws + OFF_SC + b * 16;
        sc[0] = softplusf(sums[0] + a.bb_w[0]);
        sc[1] = sigmoidf(sums[1] + a.bg_w[0]);
        sc[2] = softplusf(sums[2] + a.bgam_w[0]) + 1.f;
        sc[3] = sqrtf(sums[12]);
        sc[4] = softplusf(sums[6] + a.bb_r[0]);
        sc[5] = sigmoidf(sums[7] + a.bg_r[0]);
        sc[6] = softplusf(sums[8] + a.bgam_r[0]) + 1.f;
        sc[7] = sqrtf(sums[13]);
        {
            const float v0 = sums[3] + a.bs_w[0], v1 = sums[4] + a.bs_w[1], v2 = sums[5] + a.bs_w[2];
            const float m = fmaxf(fmaxf(v0, v1), v2);
            const float e0 = __expf(v0 - m), e1 = __expf(v1 - m), e2 = __expf(v2 - m);
            const float s = e0 + e1 + e2;
            sc[8] = e0 / s; sc[9] = e1 / s; sc[10] = e2 / s;
        }
        sc[11] = sums[14];
        {
            const float v0 = sums[9] + a.bs_r[0], v1 = sums[10] + a.bs_r[1], v2 = sums[11] + a.bs_r[2];
            const float m = fmaxf(fmaxf(v0, v1), v2);
            const float e0 = __expf(v0 - m), e1 = __expf(v1 - m), e2 = __expf(v2 - m);
            const float s = e0 + e1 + e2;
            sc[12] = e0 / s; sc[13] = e1 / s; sc[14] = e2 / s;
        }
        sc[15] = sums[15];
    }
}

// streaming pass v3: zero in-loop cross-lane ops. Each wave owns a private
// 64-row tile; lane (cg,rr) accumulates 6 partials for 8 row-sets in registers;
// one LDS transpose ([64][49], 2-way conflict-free) hands each lane a full row
// for the finalize (xw, online m/s, coalesced packed stores).
__global__ __launch_bounds__(256) void k_pass1(const float* __restrict__ mem,
                                               float* __restrict__ ws) {
    __shared__ float tr[4][64 * 49];     // 50176 B
    __shared__ float wm[4], wsum[4];
    const int t = threadIdx.x;
    const int wv = t >> 6, lane = t & 63;
    const int cg = lane & 7;             // col group 0..7 (8 cols each)
    const int rr = lane >> 3;            // row-within-set 0..7
    const int tile = (blockIdx.x << 2) + wv;     // 8192 tiles, 1 per wave
    const int rowbase = tile << 6;               // 64 rows per tile
    const int b = rowbase >> 13;
    const int cb = cg << 3;

    const float4 kwA = *(const float4*)(ws + OFF_KW + (b << 6) + cb);
    const float4 kwB = *(const float4*)(ws + OFF_KW + (b << 6) + cb + 4);
    const float4 krA = *(const float4*)(ws + OFF_KR + (b << 6) + cb);
    const float4 krB = *(const float4*)(ws + OFF_KR + (b << 6) + cb + 4);
    const float4 evA = *(const float4*)(ws + OFF_ER + (b << 6) + cb);
    const float4 evB = *(const float4*)(ws + OFF_ER + (b << 6) + cb + 4);
    const float4 avA = *(const float4*)(ws + OFF_AD + (b << 6) + cb);
    const float4 avB = *(const float4*)(ws + OFF_AD + (b << 6) + cb + 4);
    const float beta = ws[OFF_SC + b * 16 + 0];
    const float kn   = ws[OFF_SC + b * 16 + 3];

    float acc[8][6];
    #pragma unroll
    for (int s = 0; s < 8; ++s) {
        const int row = rowbase + (s << 3) + rr;
        const float* mp = mem + ((size_t)row << 6) + cb;
        const float4 m0 = *(const float4*)(mp);
        const float4 m1 = *(const float4*)(mp + 4);
        float dw = 0.f, dr = 0.f, nq = 0.f, e1 = 0.f, e2 = 0.f, c5 = 0.f;
        #define ACC(mv, kwv, krv, evv, avv) { \
            const float me = (mv) * (evv); \
            dw = fmaf((mv), (kwv), dw); \
            dr = fmaf((mv), (krv), dr); \
            nq = fmaf((mv), (mv), nq); \
            e1 = fmaf((mv), (avv) - me, e1); \
            e2 = fmaf(me, fmaf(-2.f, (avv), me), e2); \
            c5 = fmaf(me, (krv), c5); }
        ACC(m0.x, kwA.x, krA.x, evA.x, avA.x)
        ACC(m0.y, kwA.y, krA.y, evA.y, avA.y)
        ACC(m0.z, kwA.z, krA.z, evA.z, avA.z)
        ACC(m0.w, kwA.w, krA.w, evA.w, avA.w)
        ACC(m1.x, kwB.x, krB.x, evB.x, avB.x)
        ACC(m1.y, kwB.y, krB.y, evB.y, avB.y)
        ACC(m1.z, kwB.z, krB.z, evB.z, avB.z)
        ACC(m1.w, kwB.w, krB.w, evB.w, avB.w)
        #undef ACC
        acc[s][0] = dw; acc[s][1] = dr; acc[s][2] = nq;
        acc[s][3] = e1; acc[s][4] = e2; acc[s][5] = c5;
    }

    // transpose partials through LDS: [row-in-tile][cg*6+v], row stride 49
    float* T = tr[wv];
    #pragma unroll
    for (int s = 0; s < 8; ++s) {
        #pragma unroll
        for (int v = 0; v < 6; ++v)
            T[((s << 3) + rr) * 49 + cg * 6 + v] = acc[s][v];
    }
    __syncthreads();

    // lane 'lane' finalizes row rowbase+lane
    float dw = 0.f, dr = 0.f, nq = 0.f, e1 = 0.f, e2 = 0.f, c5 = 0.f;
    #pragma unroll
    for (int g = 0; g < 8; ++g) {
        const float* p = T + lane * 49 + g * 6;
        dw += p[0]; dr += p[1]; nq += p[2];
        e1 += p[3]; e2 += p[4]; c5 += p[5];
    }
    const int row = rowbase + lane;
    const float xw = beta * dw / (sqrtf(nq) * kn + EPSF);
    {
        float4 p4; p4.x = xw; p4.y = dr; p4.z = c5; p4.w = nq;
        *(float4*)(ws + OFF_P4 + ((size_t)row << 2)) = p4;
        float2 p2; p2.x = e1; p2.y = e2;
        *(float2*)(ws + OFF_P2 + ((size_t)row << 1)) = p2;
    }

    // per-wave online softmax (one value per lane)
    float om = xw, os = 1.f;
    #pragma unroll
    for (int mk = 1; mk <= 32; mk <<= 1) {
        const float m2 = __shfl_xor(om, mk), s2 = __shfl_xor(os, mk);
        msCombine(om, os, m2, s2);
    }
    if (lane == 0) { wm[wv] = om; wsum[wv] = os; }
    __syncthreads();
    if (t == 0) {
        float M = wm[0], S = wsum[0];
        msCombine(M, S, wm[1], wsum[1]);
        msCombine(M, S, wm[2], wsum[2]);
        msCombine(M, S, wm[3], wsum[3]);
        ws[OFF_MS + (blockIdx.x << 1)]     = M;
        ws[OFF_MS + (blockIdx.x << 1) + 1] = S;
    }
}

// W-side finalize: 2048 blocks x 256 thr; each block owns 256 rows of one batch.
__global__ __launch_bounds__(256) void k_wside(const float* __restrict__ prevw_w,
                                               float* __restrict__ ws) {
    __shared__ float wgbuf[258];
    __shared__ float red[6];   // [0..3] powsum, [4] M, [5] invS
    const int blk = blockIdx.x, t = threadIdx.x;
    const int b = blk >> 5;
    const int rbl = (blk & 31) << 8;
    const int bN = b * Nn;

    if (t < 64) {   // wave 0 combines the 32 online pairs
        float m = -1e30f, s = 0.f;
        if (t < 32) {
            m = ws[OFF_MS + (((b << 5) + t) << 1)];
            s = ws[OFF_MS + (((b << 5) + t) << 1) + 1];
        }
        #pragma unroll
        for (int mk = 1; mk <= 32; mk <<= 1) {
            const float m2 = __shfl_xor(m, mk), s2 = __shfl_xor(s, mk);
            msCombine(m, s, m2, s2);
        }
        if (t == 0) { red[4] = m; red[5] = 1.f / s; }
    }
    __syncthreads();
    const float M = red[4], invS = red[5];
    const float* sc = ws + OFF_SC + b * 16;
    const float g = sc[1], gam = sc[2];
    const float s0 = sc[8], s1 = sc[9], s2 = sc[10];

    auto wg_at = [&](int i) {   // i in [0,258) maps to local row (rbl+i-1) mod N
        const int rg = bN + ((rbl + i - 1) & (Nn - 1));
        const float xw = ws[OFF_P4 + ((size_t)rg << 2)];
        return g * __expf(xw - M) * invS + (1.f - g) * prevw_w[rg];
    };
    wgbuf[t + 1] = wg_at(t + 1);
    if (t == 0)   wgbuf[0]   = wg_at(0);
    if (t == 255) wgbuf[257] = wg_at(257);
    __syncthreads();

    const float wsv = s0 * wgbuf[t + 2] + s1 * wgbuf[t + 1] + s2 * wgbuf[t];
    const float wp = __expf(gam * __logf(wsv));
    ws[OFF_WPW + bN + rbl + t] = wp;

    float v = wp;
    #pragma unroll
    for (int mk = 1; mk <= 32; mk <<= 1) v += __shfl_xor(v, mk);
    if ((t & 63) == 0) red[t >> 6] = v;
    __syncthreads();
    if (t == 0) ws[OFF_PW + blk] = red[0] + red[1] + red[2] + red[3];
}

// R-side sim: normalize ww, expanded cosine sim vs new_mem, online {M,S} partials.
__global__ __launch_bounds__(256) void k_rside(float* __restrict__ ws) {
    __shared__ float redm[4], reds[4];
    __shared__ float inv[1];
    const int blk = blockIdx.x, t = threadIdx.x;
    const int b = blk >> 5;
    const int rbl = (blk & 31) << 8;
    const int bN = b * Nn;

    if (t < 64) {
        float v = (t < 32) ? ws[OFF_PW + (b << 5) + t] : 0.f;
        #pragma unroll
        for (int mk = 1; mk <= 32; mk <<= 1) v += __shfl_xor(v, mk);
        if (t == 0) inv[0] = 1.f / (v + EPSF);
    }
    __syncthreads();
    const float invW = inv[0];
    const float* sc = ws + OFF_SC + b * 16;
    const float beta_r = sc[4], kn_r = sc[7], AK = sc[11], A2 = sc[15];

    const int row = bN + rbl + t;
    const float ww = ws[OFF_WPW + row] * invW;
    const float4 p4 = *(const float4*)(ws + OFF_P4 + ((size_t)row << 2));
    const float2 p2 = *(const float2*)(ws + OFF_P2 + ((size_t)row << 1));
    const float d = p4.y + ww * (AK - p4.z);
    float qq = p4.w + 2.f * ww * p2.x + ww * ww * (p2.y + A2);
    qq = fmaxf(qq, 0.f);
    const float x = beta_r * d / (sqrtf(qq) * kn_r + EPSF);
    ws[OFF_P2 + ((size_t)row << 1)] = x;    // x_r into the e1 slot

    float om = x, os = 1.f;
    #pragma unroll
    for (int mk = 1; mk <= 32; mk <<= 1) {
        const float m2 = __shfl_xor(om, mk), s2 = __shfl_xor(os, mk);
        msCombine(om, os, m2, s2);
    }
    if ((t & 63) == 0) { redm[t >> 6] = om; reds[t >> 6] = os; }
    __syncthreads();
    if (t == 0) {
        float M = redm[0], S = reds[0];
        msCombine(M, S, redm[1], reds[1]);
        msCombine(M, S, redm[2], reds[2]);
        msCombine(M, S, redm[3], reds[3]);
        ws[OFF_MSR + (blk << 1)]     = M;
        ws[OFF_MSR + (blk << 1) + 1] = S;
    }
}

// R-side finalize: wg_r halo -> shift -> wpow_r (stored) + powsum partial.
__global__ __launch_bounds__(256) void k_rfin(const float* __restrict__ prevw_r,
                                              float* __restrict__ ws) {
    __shared__ float wgbuf[258];
    __shared__ float red[6];
    const int blk = blockIdx.x, t = threadIdx.x;
    const int b = blk >> 5;
    const int rbl = (blk & 31) << 8;
    const int bN = b * Nn;

    if (t < 64) {
        float m = -1e30f, s = 0.f;
        if (t < 32) {
            m = ws[OFF_MSR + (((b << 5) + t) << 1)];
            s = ws[OFF_MSR + (((b << 5) + t) << 1) + 1];
        }
        #pragma unroll
        for (int mk = 1; mk <= 32; mk <<= 1) {
            const float m2 = __shfl_xor(m, mk), s2 = __shfl_xor(s, mk);
            msCombine(m, s, m2, s2);
        }
        if (t == 0) { red[4] = m; red[5] = 1.f / s; }
    }
    __syncthreads();
    const float M = red[4], invS = red[5];
    const float* sc = ws + OFF_SC + b * 16;
    const float g = sc[5], gam = sc[6];
    const float s0 = sc[12], s1 = sc[13], s2 = sc[14];

    auto wg_at = [&](int i) {
        const int rg = bN + ((rbl + i - 1) & (Nn - 1));
        const float xr = ws[OFF_P2 + ((size_t)rg << 1)];
        return g * __expf(xr - M) * invS + (1.f - g) * prevw_r[rg];
    };
    wgbuf[t + 1] = wg_at(t + 1);
    if (t == 0)   wgbuf[0]   = wg_at(0);
    if (t == 255) wgbuf[257] = wg_at(257);
    __syncthreads();

    const float wsv = s0 * wgbuf[t + 2] + s1 * wgbuf[t + 1] + s2 * wgbuf[t];
    const float wp = __expf(gam * __logf(wsv));
    ws[OFF_WPR + bN + rbl + t] = wp;

    float v = wp;
    #pragma unroll
    for (int mk = 1; mk <= 32; mk <<= 1) v += __shfl_xor(v, mk);
    if ((t & 63) == 0) red[t >> 6] = v;
    __syncthreads();
    if (t == 0) ws[OFF_PR + blk] = red[0] + red[1] + red[2] + red[3];
}

// read-vector partials: recompute new_mem on the fly (second & last mem pass)
__global__ __launch_bounds__(256) void k_read(const float* __restrict__ mem,
                                              float* __restrict__ ws) {
    __shared__ float lds[4 * 64];
    __shared__ float invb[2];
    const int b = blockIdx.x >> 5;
    const int chunk = blockIdx.x & 31;
    const int t = threadIdx.x;
    const int lane = t & 63, wv = t >> 6;
    const int q = lane & 15, r = lane >> 4;

    if (t < 64) {
        float vw = (t < 32) ? ws[OFF_PW + (b << 5) + t] : 0.f;
        float vr = (t < 32) ? ws[OFF_PR + (b << 5) + t] : 0.f;
        #pragma unroll
        for (int mk = 1; mk <= 32; mk <<= 1) { vw += __shfl_xor(vw, mk); vr += __shfl_xor(vr, mk); }
        if (t == 0) { invb[0] = 1.f / (vw + EPSF); invb[1] = 1.f / (vr + EPSF); }
    }
    __syncthreads();
    const float invW = invb[0], invR = invb[1];

    const float4 evv = *(const float4*)(ws + OFF_ER + (b << 6) + (q << 2));
    const float4 avv = *(const float4*)(ws + OFF_AD + (b << 6) + (q << 2));
    float a0 = 0.f, a1 = 0.f, a2 = 0.f, a3 = 0.f;
    const int base_n = chunk << 8;
    #pragma unroll 4
    for (int gi = wv; gi < 64; gi += 4) {
        const int n = base_n + (gi << 2) + r;
        const int row = b * Nn + n;
        const float4 mv = *(const float4*)(mem + ((size_t)row << 6) + (q << 2));
        const float w   = ws[OFF_WPW + row] * invW;
        const float wrv = ws[OFF_WPR + row] * invR;
        a0 = fmaf((mv.x * (1.f - w * evv.x) + w * avv.x), wrv, a0);
        a1 = fmaf((mv.y * (1.f - w * evv.y) + w * avv.y), wrv, a1);
        a2 = fmaf((mv.z * (1.f - w * evv.z) + w * avv.z), wrv, a2);
        a3 = fmaf((mv.w * (1.f - w * evv.w) + w * avv.w), wrv, a3);
    }
    #pragma unroll
    for (int m = 16; m <= 32; m <<= 1) {
        a0 += __shfl_xor(a0, m); a1 += __shfl_xor(a1, m);
        a2 += __shfl_xor(a2, m); a3 += __shfl_xor(a3, m);
    }
    if (r == 0) {
        lds[wv * 64 + q * 4 + 0] = a0; lds[wv * 64 + q * 4 + 1] = a1;
        lds[wv * 64 + q * 4 + 2] = a2; lds[wv * 64 + q * 4 + 3] = a3;
    }
    __syncthreads();
    if (t < 64) {
        ws[OFF_PT + blockIdx.x * 64 + t] = lds[t] + lds[64 + t] + lds[128 + t] + lds[192 + t];
    }
}

__global__ __launch_bounds__(64) void k_reduce(const float* __restrict__ ws,
                                               float* __restrict__ out) {
    const int b = blockIdx.x, d = threadIdx.x;
    float s = 0.f;
    #pragma unroll
    for (int i = 0; i < 32; ++i) s += ws[OFF_PT + ((b << 5) + i) * 64 + d];
    out[b * OUTW + 256 + d] = s;
}

extern "C" void kernel_launch(void* const* d_in, const int* in_sizes, int n_in,
                              void* d_out, int out_size, void* d_ws, size_t ws_size,
                              hipStream_t stream) {
    const float* x      = (const float*)d_in[0];
    const float* mem    = (const float*)d_in[1];
    const float* prw_r  = (const float*)d_in[2];
    const float* prw_w  = (const float*)d_in[3];
    const float* prv    = (const float*)d_in[4];

    float* ws  = (float*)d_ws;
    float* out = (float*)d_out;

    SetupArgs a;
    a.x = x; a.prv = prv;
    a.Wc = (const float*)d_in[5];  a.bc = (const float*)d_in[6];
    a.Wk_r = (const float*)d_in[7];  a.bk_r = (const float*)d_in[8];
    a.Wb_r = (const float*)d_in[9];  a.bb_r = (const float*)d_in[10];
    a.Wg_r = (const float*)d_in[11]; a.bg_r = (const float*)d_in[12];
    a.Ws_r = (const float*)d_in[13]; a.bs_r = (const float*)d_in[14];
    a.Wgam_r = (const float*)d_in[15]; a.bgam_r = (const float*)d_in[16];
    a.Wk_w = (const float*)d_in[17]; a.bk_w = (const float*)d_in[18];
    a.Wb_w = (const float*)d_in[19]; a.bb_w = (const float*)d_in[20];
    a.Wg_w = (const float*)d_in[21]; a.bg_w = (const float*)d_in[22];
    a.Ws_w = (const float*)d_in[23]; a.bs_w = (const float*)d_in[24];
    a.Wgam_w = (const float*)d_in[25]; a.bgam_w = (const float*)d_in[26];
    a.We_w = (const float*)d_in[27]; a.be_w = (const float*)d_in[28];
    a.Wa_w = (const float*)d_in[29]; a.ba_w = (const float*)d_in[30];
    a.ws = ws; a.out = out;

    k_setup <<<Bb,   256, 0, stream>>>(a);
    k_pass1 <<<2048, 256, 0, stream>>>(mem, ws);
    k_wside <<<2048, 256, 0, stream>>>(prw_w, ws);
    k_rside <<<2048, 256, 0, stream>>>(ws);
    k_rfin  <<<2048, 256, 0, stream>>>(prw_r, ws);
    k_read  <<<2048, 256, 0, stream>>>(mem, ws);
    k_reduce<<<Bb,   64,  0, stream>>>(ws, out);
}

// Round 8
// 83.110 us; speedup vs baseline: 1.0892x; 1.0002x over previous
//
#include <hip/hip_runtime.h>
#include <math.h>

#define Bb   64
#define Nn   8192
#define Dd   64
#define Cc   256
#define INn  128
#define CTRL 192
#define OUTW 320
#define EPSF 1e-8f
#define BN   (Bb*Nn)

// ---------------- workspace layout (floats) ----------------
#define OFF_XW  0                     // x_w = beta*sim (SoA, dense)       [BN]
#define OFF_P4  BN                    // packed per-row {dr,c5,nq,e1}      [BN*4]
#define OFF_E2  (5*BN)                // e2                                 [BN]
#define OFF_XR  (6*BN)                // x_r (written by rside, dense)     [BN]
#define OFF_WPW (7*BN)                // unnormalized wpow_w               [BN]
#define OFF_WPR (8*BN)                // unnormalized wpow_r               [BN]
#define OFF_PT  (9*BN)                // read-vec partials                 [2048*64]
#define OFF_MS  (OFF_PT + 131072)     // W-side online {M,S} per p1 block  [4096*2]
#define OFF_PW  (OFF_MS + 8192)       // W-side powsum partials            [2048]
#define OFF_MSR (OFF_PW + 2048)       // R-side online {M,S} per block     [2048*2]
#define OFF_PR  (OFF_MSR + 4096)      // R-side powsum partials            [2048]
#define OFF_KW  (OFF_PR + 2048)       // k_w                               [B*D]
#define OFF_KR  (OFF_KW + Bb*Dd)      // k_r                               [B*D]
#define OFF_ER  (OFF_KR + Bb*Dd)      // erase (post-sigmoid)              [B*D]
#define OFF_AD  (OFF_ER + Bb*Dd)      // add (post-tanh)                   [B*D]
#define OFF_SC  (OFF_AD + Bb*Dd)      // per-b scalars                     [B*16]
// per-b scalars: 0..3 beta_w,g_w,gam_w,knorm_w | 4..7 beta_r,g_r,gam_r,knorm_r
//                8..10 s_w | 11 AK=a.k_r | 12..14 s_r | 15 A2=|a|^2

__device__ __forceinline__ float softplusf(float x) {
    return (x > 20.f) ? x : log1pf(__expf(x));
}
__device__ __forceinline__ float sigmoidf(float x) {
    return 1.f / (1.f + __expf(-x));
}
// online-softmax pair combine: (m,s) <- (m,s) (+) (m2,s2)
__device__ __forceinline__ void msCombine(float& m, float& s, float m2, float s2) {
    const float mn = fmaxf(m, m2);
    s = s * __expf(m - mn) + s2 * __expf(m2 - mn);
    m = mn;
}

struct SetupArgs {
    const float *x, *prv, *Wc, *bc;
    const float *Wk_r, *bk_r, *Wb_r, *bb_r, *Wg_r, *bg_r, *Ws_r, *bs_r, *Wgam_r, *bgam_r;
    const float *Wk_w, *bk_w, *Wb_w, *bb_w, *Wg_w, *bg_w, *Ws_w, *bs_w, *Wgam_w, *bgam_w;
    const float *We_w, *be_w, *Wa_w, *ba_w;
    float *ws, *out;
};

// one block per batch: controller GEMM + projections + batched scalar reductions
__global__ __launch_bounds__(256) void k_setup(SetupArgs a) {
    __shared__ float ci[CTRL];
    __shared__ float h[Cc];
    __shared__ alignas(16) float kbuf[128];
    __shared__ alignas(16) float abuf[64];
    __shared__ float red[4][16];
    __shared__ float sums[16];
    const int b = blockIdx.x, t = threadIdx.x;

    if (t < INn)       ci[t] = a.x[b * INn + t];
    else if (t < CTRL) ci[t] = a.prv[b * Dd + (t - INn)];
    __syncthreads();

    float acc = a.bc[t];
    #pragma unroll 16
    for (int i = 0; i < CTRL; ++i) acc += ci[i] * a.Wc[i * Cc + t];
    const float hv = fmaxf(acc, 0.f);
    h[t] = hv;
    a.out[b * OUTW + t] = hv;
    __syncthreads();

    {
        const int job = t >> 6, d = t & 63;
        const float* W  = (job == 0) ? a.Wk_w : (job == 1) ? a.Wk_r : (job == 2) ? a.We_w : a.Wa_w;
        const float* bs = (job == 0) ? a.bk_w : (job == 1) ? a.bk_r : (job == 2) ? a.be_w : a.ba_w;
        float p = bs[d];
        #pragma unroll 16
        for (int c = 0; c < Cc; ++c) p += h[c] * W[c * Dd + d];
        if (job == 0)      { a.ws[OFF_KW + b * Dd + d] = p; kbuf[d] = p; }
        else if (job == 1) { a.ws[OFF_KR + b * Dd + d] = p; kbuf[64 + d] = p; }
        else if (job == 2) { a.ws[OFF_ER + b * Dd + d] = sigmoidf(p); }
        else               { const float ad = tanhf(p); a.ws[OFF_AD + b * Dd + d] = ad; abuf[d] = ad; }
    }
    __syncthreads();

    float v[16];
    v[0] = hv * a.Wb_w[t];  v[1] = hv * a.Wg_w[t];  v[2] = hv * a.Wgam_w[t];
    v[3] = hv * a.Ws_w[t * 3 + 0]; v[4] = hv * a.Ws_w[t * 3 + 1]; v[5] = hv * a.Ws_w[t * 3 + 2];
    v[6] = hv * a.Wb_r[t];  v[7] = hv * a.Wg_r[t];  v[8] = hv * a.Wgam_r[t];
    v[9] = hv * a.Ws_r[t * 3 + 0]; v[10] = hv * a.Ws_r[t * 3 + 1]; v[11] = hv * a.Ws_r[t * 3 + 2];
    v[12] = (t < 64) ? kbuf[t] * kbuf[t] : 0.f;
    v[13] = (t >= 64 && t < 128) ? kbuf[t] * kbuf[t] : 0.f;
    v[14] = (t < 64) ? abuf[t] * kbuf[64 + t] : 0.f;
    v[15] = (t < 64) ? abuf[t] * abuf[t] : 0.f;
    #pragma unroll
    for (int k = 0; k < 16; ++k) {
        #pragma unroll
        for (int m = 32; m >= 1; m >>= 1) v[k] += __shfl_xor(v[k], m);
    }
    if ((t & 63) == 0) {
        #pragma unroll
        for (int k = 0; k < 16; ++k) red[t >> 6][k] = v[k];
    }
    __syncthreads();
    if (t < 16) sums[t] = red[0][t] + red[1][t] + red[2][t] + red[3][t];
    __syncthreads();

    if (t == 0) {
        float* sc = a.ws + OFF_SC + b * 16;
        sc[0] = softplusf(sums[0] + a.bb_w[0]);
        sc[1] = sigmoidf(sums[1] + a.bg_w[0]);
        sc[2] = softplusf(sums[2] + a.bgam_w[0]) + 1.f;
        sc[3] = sqrtf(sums[12]);
        sc[4] = softplusf(sums[6] + a.bb_r[0]);
        sc[5] = sigmoidf(sums[7] + a.bg_r[0]);
        sc[6] = softplusf(sums[8] + a.bgam_r[0]) + 1.f;
        sc[7] = sqrtf(sums[13]);
        {
            const float v0 = sums[3] + a.bs_w[0], v1 = sums[4] + a.bs_w[1], v2 = sums[5] + a.bs_w[2];
            const float m = fmaxf(fmaxf(v0, v1), v2);
            const float e0 = __expf(v0 - m), e1 = __expf(v1 - m), e2 = __expf(v2 - m);
            const float s = e0 + e1 + e2;
            sc[8] = e0 / s; sc[9] = e1 / s; sc[10] = e2 / s;
        }
        sc[11] = sums[14];
        {
            const float v0 = sums[9] + a.bs_r[0], v1 = sums[10] + a.bs_r[1], v2 = sums[11] + a.bs_r[2];
            const float m = fmaxf(fmaxf(v0, v1), v2);
            const float e0 = __expf(v0 - m), e1 = __expf(v1 - m), e2 = __expf(v2 - m);
            const float s = e0 + e1 + e2;
            sc[12] = e0 / s; sc[13] = e1 / s; sc[14] = e2 / s;
        }
        sc[15] = sums[15];
    }
}

// streaming pass v4: 4096 blocks, one 32-row tile per wave (24 waves/CU).
// Register accumulation (acc[4][6]) -> [32][49] LDS transpose (2-way, free)
// -> 2 lanes/row finalize -> dense SoA stores + per-block online {M,S}.
__global__ __launch_bounds__(256) void k_pass1(const float* __restrict__ mem,
                                               float* __restrict__ ws) {
    __shared__ float tr[4][32 * 49];     // 25,088 B
    __shared__ float wm[4], wsum[4];
    const int t = threadIdx.x;
    const int wv = t >> 6, lane = t & 63;
    const int cg = lane & 7;             // col group 0..7 (8 cols each)
    const int rr = lane >> 3;            // row-within-set 0..7
    const int tile = (blockIdx.x << 2) + wv;     // 16384 tiles of 32 rows
    const int rowbase = tile << 5;
    const int b = rowbase >> 13;
    const int cb = cg << 3;

    const float4 kwA = *(const float4*)(ws + OFF_KW + (b << 6) + cb);
    const float4 kwB = *(const float4*)(ws + OFF_KW + (b << 6) + cb + 4);
    const float4 krA = *(const float4*)(ws + OFF_KR + (b << 6) + cb);
    const float4 krB = *(const float4*)(ws + OFF_KR + (b << 6) + cb + 4);
    const float4 evA = *(const float4*)(ws + OFF_ER + (b << 6) + cb);
    const float4 evB = *(const float4*)(ws + OFF_ER + (b << 6) + cb + 4);
    const float4 avA = *(const float4*)(ws + OFF_AD + (b << 6) + cb);
    const float4 avB = *(const float4*)(ws + OFF_AD + (b << 6) + cb + 4);
    const float beta = ws[OFF_SC + b * 16 + 0];
    const float kn   = ws[OFF_SC + b * 16 + 3];

    float acc[4][6];
    #pragma unroll
    for (int s = 0; s < 4; ++s) {
        const int row = rowbase + (s << 3) + rr;
        const float* mp = mem + ((size_t)row << 6) + cb;
        const float4 m0 = *(const float4*)(mp);
        const float4 m1 = *(const float4*)(mp + 4);
        float dw = 0.f, dr = 0.f, nq = 0.f, e1 = 0.f, e2 = 0.f, c5 = 0.f;
        #define ACC(mv, kwv, krv, evv, avv) { \
            const float me = (mv) * (evv); \
            dw = fmaf((mv), (kwv), dw); \
            dr = fmaf((mv), (krv), dr); \
            nq = fmaf((mv), (mv), nq); \
            e1 = fmaf((mv), (avv) - me, e1); \
            e2 = fmaf(me, fmaf(-2.f, (avv), me), e2); \
            c5 = fmaf(me, (krv), c5); }
        ACC(m0.x, kwA.x, krA.x, evA.x, avA.x)
        ACC(m0.y, kwA.y, krA.y, evA.y, avA.y)
        ACC(m0.z, kwA.z, krA.z, evA.z, avA.z)
        ACC(m0.w, kwA.w, krA.w, evA.w, avA.w)
        ACC(m1.x, kwB.x, krB.x, evB.x, avB.x)
        ACC(m1.y, kwB.y, krB.y, evB.y, avB.y)
        ACC(m1.z, kwB.z, krB.z, evB.z, avB.z)
        ACC(m1.w, kwB.w, krB.w, evB.w, avB.w)
        #undef ACC
        acc[s][0] = dw; acc[s][1] = dr; acc[s][2] = nq;
        acc[s][3] = e1; acc[s][4] = e2; acc[s][5] = c5;
    }

    // transpose partials through LDS: row-in-tile r = s*8+rr, col = cg*6+v
    float* T = tr[wv];
    #pragma unroll
    for (int s = 0; s < 4; ++s) {
        #pragma unroll
        for (int v = 0; v < 6; ++v)
            T[((s << 3) + rr) * 49 + cg * 6 + v] = acc[s][v];
    }
    __syncthreads();

    // 2 lanes per row: lane&31 picks the row, lane>>5 picks which 4 col-groups
    const int rd = lane & 31;
    const int gb = (lane >> 5) << 2;    // 0 or 4
    float dw = 0.f, dr = 0.f, nq = 0.f, e1 = 0.f, e2 = 0.f, c5 = 0.f;
    #pragma unroll
    for (int g = 0; g < 4; ++g) {
        const float* p = T + rd * 49 + (gb + g) * 6;
        dw += p[0]; dr += p[1]; nq += p[2];
        e1 += p[3]; e2 += p[4]; c5 += p[5];
    }
    dw += __shfl_xor(dw, 32); dr += __shfl_xor(dr, 32); nq += __shfl_xor(nq, 32);
    e1 += __shfl_xor(e1, 32); e2 += __shfl_xor(e2, 32); c5 += __shfl_xor(c5, 32);

    const int row = rowbase + rd;
    const float xw = beta * dw / (sqrtf(nq) * kn + EPSF);
    if (lane < 32) {
        ws[OFF_XW + row] = xw;
        float4 p4; p4.x = dr; p4.y = c5; p4.z = nq; p4.w = e1;
        *(float4*)(ws + OFF_P4 + ((size_t)row << 2)) = p4;
        ws[OFF_E2 + row] = e2;
    }

    // per-wave online softmax (each row duplicated 2x -> halve S at the end)
    float om = xw, os = 1.f;
    #pragma unroll
    for (int mk = 1; mk <= 32; mk <<= 1) {
        const float m2 = __shfl_xor(om, mk), s2 = __shfl_xor(os, mk);
        msCombine(om, os, m2, s2);
    }
    if (lane == 0) { wm[wv] = om; wsum[wv] = os; }
    __syncthreads();
    if (t == 0) {
        float M = wm[0], S = wsum[0];
        msCombine(M, S, wm[1], wsum[1]);
        msCombine(M, S, wm[2], wsum[2]);
        msCombine(M, S, wm[3], wsum[3]);
        ws[OFF_MS + (blockIdx.x << 1)]     = M;
        ws[OFF_MS + (blockIdx.x << 1) + 1] = S * 0.5f;
    }
}

// W-side finalize: 2048 blocks x 256 thr; each block owns 256 rows of one batch.
__global__ __launch_bounds__(256) void k_wside(const float* __restrict__ prevw_w,
                                               float* __restrict__ ws) {
    __shared__ float wgbuf[258];
    __shared__ float red[6];   // [0..3] powsum, [4] M, [5] invS
    const int blk = blockIdx.x, t = threadIdx.x;
    const int b = blk >> 5;
    const int rbl = (blk & 31) << 8;
    const int bN = b * Nn;

    if (t < 64) {   // wave 0 combines the 64 online pairs of this batch
        float m = ws[OFF_MS + ((b * 64 + t) << 1)];
        float s = ws[OFF_MS + ((b * 64 + t) << 1) + 1];
        #pragma unroll
        for (int mk = 1; mk <= 32; mk <<= 1) {
            const float m2 = __shfl_xor(m, mk), s2 = __shfl_xor(s, mk);
            msCombine(m, s, m2, s2);
        }
        if (t == 0) { red[4] = m; red[5] = 1.f / s; }
    }
    __syncthreads();
    const float M = red[4], invS = red[5];
    const float* sc = ws + OFF_SC + b * 16;
    const float g = sc[1], gam = sc[2];
    const float s0 = sc[8], s1 = sc[9], s2 = sc[10];

    auto wg_at = [&](int i) {   // i in [0,258) maps to local row (rbl+i-1) mod N
        const int rg = bN + ((rbl + i - 1) & (Nn - 1));
        return g * __expf(ws[OFF_XW + rg] - M) * invS + (1.f - g) * prevw_w[rg];
    };
    wgbuf[t + 1] = wg_at(t + 1);
    if (t == 0)   wgbuf[0]   = wg_at(0);
    if (t == 255) wgbuf[257] = wg_at(257);
    __syncthreads();

    const float wsv = s0 * wgbuf[t + 2] + s1 * wgbuf[t + 1] + s2 * wgbuf[t];
    const float wp = __expf(gam * __logf(wsv));
    ws[OFF_WPW + bN + rbl + t] = wp;

    float v = wp;
    #pragma unroll
    for (int mk = 1; mk <= 32; mk <<= 1) v += __shfl_xor(v, mk);
    if ((t & 63) == 0) red[t >> 6] = v;
    __syncthreads();
    if (t == 0) ws[OFF_PW + blk] = red[0] + red[1] + red[2] + red[3];
}

// R-side sim: normalize ww, expanded cosine sim vs new_mem, online {M,S} partials.
__global__ __launch_bounds__(256) void k_rside(float* __restrict__ ws) {
    __shared__ float redm[4], reds[4];
    __shared__ float inv[1];
    const int blk = blockIdx.x, t = threadIdx.x;
    const int b = blk >> 5;
    const int rbl = (blk & 31) << 8;
    const int bN = b * Nn;

    if (t < 64) {
        float v = (t < 32) ? ws[OFF_PW + (b << 5) + t] : 0.f;
        #pragma unroll
        for (int mk = 1; mk <= 32; mk <<= 1) v += __shfl_xor(v, mk);
        if (t == 0) inv[0] = 1.f / (v + EPSF);
    }
    __syncthreads();
    const float invW = inv[0];
    const float* sc = ws + OFF_SC + b * 16;
    const float beta_r = sc[4], kn_r = sc[7], AK = sc[11], A2 = sc[15];

    const int row = bN + rbl + t;
    const float ww = ws[OFF_WPW + row] * invW;
    const float4 p4 = *(const float4*)(ws + OFF_P4 + ((size_t)row << 2)); // dr,c5,nq,e1
    const float e2 = ws[OFF_E2 + row];
    const float d = p4.x + ww * (AK - p4.y);
    float qq = p4.z + 2.f * ww * p4.w + ww * ww * (e2 + A2);
    qq = fmaxf(qq, 0.f);
    const float x = beta_r * d / (sqrtf(qq) * kn_r + EPSF);
    ws[OFF_XR + row] = x;

    float om = x, os = 1.f;
    #pragma unroll
    for (int mk = 1; mk <= 32; mk <<= 1) {
        const float m2 = __shfl_xor(om, mk), s2 = __shfl_xor(os, mk);
        msCombine(om, os, m2, s2);
    }
    if ((t & 63) == 0) { redm[t >> 6] = om; reds[t >> 6] = os; }
    __syncthreads();
    if (t == 0) {
        float M = redm[0], S = reds[0];
        msCombine(M, S, redm[1], reds[1]);
        msCombine(M, S, redm[2], reds[2]);
        msCombine(M, S, redm[3], reds[3]);
        ws[OFF_MSR + (blk << 1)]     = M;
        ws[OFF_MSR + (blk << 1) + 1] = S;
    }
}

// R-side finalize: wg_r halo -> shift -> wpow_r (stored) + powsum partial.
__global__ __launch_bounds__(256) void k_rfin(const float* __restrict__ prevw_r,
                                              float* __restrict__ ws) {
    __shared__ float wgbuf[258];
    __shared__ float red[6];
    const int blk = blockIdx.x, t = threadIdx.x;
    const int b = blk >> 5;
    const int rbl = (blk & 31) << 8;
    const int bN = b * Nn;

    if (t < 64) {
        float m = -1e30f, s = 0.f;
        if (t < 32) {
            m = ws[OFF_MSR + (((b << 5) + t) << 1)];
            s = ws[OFF_MSR + (((b << 5) + t) << 1) + 1];
        }
        #pragma unroll
        for (int mk = 1; mk <= 32; mk <<= 1) {
            const float m2 = __shfl_xor(m, mk), s2 = __shfl_xor(s, mk);
            msCombine(m, s, m2, s2);
        }
        if (t == 0) { red[4] = m; red[5] = 1.f / s; }
    }
    __syncthreads();
    const float M = red[4], invS = red[5];
    const float* sc = ws + OFF_SC + b * 16;
    const float g = sc[5], gam = sc[6];
    const float s0 = sc[12], s1 = sc[13], s2 = sc[14];

    auto wg_at = [&](int i) {
        const int rg = bN + ((rbl + i - 1) & (Nn - 1));
        return g * __expf(ws[OFF_XR + rg] - M) * invS + (1.f - g) * prevw_r[rg];
    };
    wgbuf[t + 1] = wg_at(t + 1);
    if (t == 0)   wgbuf[0]   = wg_at(0);
    if (t == 255) wgbuf[257] = wg_at(257);
    __syncthreads();

    const float wsv = s0 * wgbuf[t + 2] + s1 * wgbuf[t + 1] + s2 * wgbuf[t];
    const float wp = __expf(gam * __logf(wsv));
    ws[OFF_WPR + bN + rbl + t] = wp;

    float v = wp;
    #pragma unroll
    for (int mk = 1; mk <= 32; mk <<= 1) v += __shfl_xor(v, mk);
    if ((t & 63) == 0) red[t >> 6] = v;
    __syncthreads();
    if (t == 0) ws[OFF_PR + blk] = red[0] + red[1] + red[2] + red[3];
}

// read-vector partials: recompute new_mem on the fly (second & last mem pass)
__global__ __launch_bounds__(256) void k_read(const float* __restrict__ mem,
                                              float* __restrict__ ws) {
    __shared__ float lds[4 * 64];
    __shared__ float invb[2];
    const int b = blockIdx.x >> 5;
    const int chunk = blockIdx.x & 31;
    const int t = threadIdx.x;
    const int lane = t & 63, wv = t >> 6;
    const int q = lane & 15, r = lane >> 4;

    if (t < 64) {
        float vw = (t < 32) ? ws[OFF_PW + (b << 5) + t] : 0.f;
        float vr = (t < 32) ? ws[OFF_PR + (b << 5) + t] : 0.f;
        #pragma unroll
        for (int mk = 1; mk <= 32; mk <<= 1) { vw += __shfl_xor(vw, mk); vr += __shfl_xor(vr, mk); }
        if (t == 0) { invb[0] = 1.f / (vw + EPSF); invb[1] = 1.f / (vr + EPSF); }
    }
    __syncthreads();
    const float invW = invb[0], invR = invb[1];

    const float4 evv = *(const float4*)(ws + OFF_ER + (b << 6) + (q << 2));
    const float4 avv = *(const float4*)(ws + OFF_AD + (b << 6) + (q << 2));
    float a0 = 0.f, a1 = 0.f, a2 = 0.f, a3 = 0.f;
    const int base_n = chunk << 8;
    #pragma unroll 4
    for (int gi = wv; gi < 64; gi += 4) {
        const int n = base_n + (gi << 2) + r;
        const int row = b * Nn + n;
        const float4 mv = *(const float4*)(mem + ((size_t)row << 6) + (q << 2));
        const float w   = ws[OFF_WPW + row] * invW;
        const float wrv = ws[OFF_WPR + row] * invR;
        a0 = fmaf((mv.x * (1.f - w * evv.x) + w * avv.x), wrv, a0);
        a1 = fmaf((mv.y * (1.f - w * evv.y) + w * avv.y), wrv, a1);
        a2 = fmaf((mv.z * (1.f - w * evv.z) + w * avv.z), wrv, a2);
        a3 = fmaf((mv.w * (1.f - w * evv.w) + w * avv.w), wrv, a3);
    }
    #pragma unroll
    for (int m = 16; m <= 32; m <<= 1) {
        a0 += __shfl_xor(a0, m); a1 += __shfl_xor(a1, m);
        a2 += __shfl_xor(a2, m); a3 += __shfl_xor(a3, m);
    }
    if (r == 0) {
        lds[wv * 64 + q * 4 + 0] = a0; lds[wv * 64 + q * 4 + 1] = a1;
        lds[wv * 64 + q * 4 + 2] = a2; lds[wv * 64 + q * 4 + 3] = a3;
    }
    __syncthreads();
    if (t < 64) {
        ws[OFF_PT + blockIdx.x * 64 + t] = lds[t] + lds[64 + t] + lds[128 + t] + lds[192 + t];
    }
}

__global__ __launch_bounds__(64) void k_reduce(const float* __restrict__ ws,
                                               float* __restrict__ out) {
    const int b = blockIdx.x, d = threadIdx.x;
    float s = 0.f;
    #pragma unroll
    for (int i = 0; i < 32; ++i) s += ws[OFF_PT + ((b << 5) + i) * 64 + d];
    out[b * OUTW + 256 + d] = s;
}

extern "C" void kernel_launch(void* const* d_in, const int* in_sizes, int n_in,
                              void* d_out, int out_size, void* d_ws, size_t ws_size,
                              hipStream_t stream) {
    const float* x      = (const float*)d_in[0];
    const float* mem    = (const float*)d_in[1];
    const float* prw_r  = (const float*)d_in[2];
    const float* prw_w  = (const float*)d_in[3];
    const float* prv    = (const float*)d_in[4];

    float* ws  = (float*)d_ws;
    float* out = (float*)d_out;

    SetupArgs a;
    a.x = x; a.prv = prv;
    a.Wc = (const float*)d_in[5];  a.bc = (const float*)d_in[6];
    a.Wk_r = (const float*)d_in[7];  a.bk_r = (const float*)d_in[8];
    a.Wb_r = (const float*)d_in[9];  a.bb_r = (const float*)d_in[10];
    a.Wg_r = (const float*)d_in[11]; a.bg_r = (const float*)d_in[12];
    a.Ws_r = (const float*)d_in[13]; a.bs_r = (const float*)d_in[14];
    a.Wgam_r = (const float*)d_in[15]; a.bgam_r = (const float*)d_in[16];
    a.Wk_w = (const float*)d_in[17]; a.bk_w = (const float*)d_in[18];
    a.Wb_w = (const float*)d_in[19]; a.bb_w = (const float*)d_in[20];
    a.Wg_w = (const float*)d_in[21]; a.bg_w = (const float*)d_in[22];
    a.Ws_w = (const float*)d_in[23]; a.bs_w = (const float*)d_in[24];
    a.Wgam_w = (const float*)d_in[25]; a.bgam_w = (const float*)d_in[26];
    a.We_w = (const float*)d_in[27]; a.be_w = (const float*)d_in[28];
    a.Wa_w = (const float*)d_in[29]; a.ba_w = (const float*)d_in[30];
    a.ws = ws; a.out = out;

    k_setup <<<Bb,   256, 0, stream>>>(a);
    k_pass1 <<<4096, 256, 0, stream>>>(mem, ws);
    k_wside <<<2048, 256, 0, stream>>>(prw_w, ws);
    k_rside <<<2048, 256, 0, stream>>>(ws);
    k_rfin  <<<2048, 256, 0, stream>>>(prw_r, ws);
    k_read  <<<2048, 256, 0, stream>>>(mem, ws);
    k_reduce<<<Bb,   64,  0, stream>>>(ws, out);
}